// Round 12
// baseline (1765.905 us; speedup 1.0000x reference)
//
#include <hip/hip_runtime.h>
#include <cstddef>
#include <cstdint>

#define Lc 33
#define Dc 2048
#define DBc 1024
#define Pc 24
#define Bc 2048

typedef __attribute__((ext_vector_type(4))) float f32x4;
typedef __attribute__((ext_vector_type(8))) short s16x8;
typedef __attribute__((ext_vector_type(4))) short s16x4;

__device__ __forceinline__ short bf16r(float f) {
  unsigned u = __float_as_uint(f);
  u = (u + 0x7fffu + ((u >> 16) & 1u)) >> 16;
  return (short)u;
}
__device__ __forceinline__ float bf2f(short s) {
  return __uint_as_float(((unsigned)(unsigned short)s) << 16);
}
__device__ __forceinline__ s16x8 pack8(const float* f) {
  s16x8 r;
#pragma unroll
  for (int i = 0; i < 8; ++i) r[i] = bf16r(f[i]);
  return r;
}
__device__ __forceinline__ void split8(const float* f, s16x8& hi, s16x8& lo) {
#pragma unroll
  for (int i = 0; i < 8; ++i) {
    short h = bf16r(f[i]);
    hi[i] = h;
    lo[i] = bf16r(f[i] - bf2f(h));
  }
}
__device__ __forceinline__ void gl_lds16(const void* g, void* l) {
  __builtin_amdgcn_global_load_lds(
      (const __attribute__((address_space(1))) unsigned int*)g,
      (__attribute__((address_space(3))) unsigned int*)l, 16, 0, 0);
}

#define BARw() __builtin_amdgcn_s_barrier()
#define VM4() asm volatile("s_waitcnt vmcnt(4)" ::: "memory")

// ---------------------------------------------------------------------------
// x [b][l][k] f32 -> xbf [z][b][k] bf16 (permuting convert)
// ---------------------------------------------------------------------------
__global__ __launch_bounds__(256)
void cvt_perm_kernel(const float* __restrict__ in,
                     unsigned short* __restrict__ outp) {
  const int row = blockIdx.x, z = blockIdx.y;
  const int k0 = threadIdx.x * 8;
  const float* src = in + ((size_t)row * Lc + z) * Dc + k0;
  f32x4 a = *(const f32x4*)(src);
  f32x4 b = *(const f32x4*)(src + 4);
  float f[8] = {a[0], a[1], a[2], a[3], b[0], b[1], b[2], b[3]};
  *(s16x8*)(outp + ((size_t)z * Bc + row) * Dc + k0) = pack8(f);
}

// ---------------------------------------------------------------------------
// keys = pos_emb @ Wk   (33 x 2048, K=24)
// ---------------------------------------------------------------------------
__global__ __launch_bounds__(256)
void keys_kernel(const float* __restrict__ pe, const float* __restrict__ Wk,
                 float* __restrict__ keys) {
  const int l = blockIdx.x;
  const int d = blockIdx.y * 256 + threadIdx.x;
  float s = 0.f;
#pragma unroll
  for (int p = 0; p < Pc; ++p) s += pe[l * Pc + p] * Wk[(size_t)p * Dc + d];
  keys[(size_t)l * Dc + d] = s;
}

// ---------------------------------------------------------------------------
// Transpose + bf16-convert W1: [z][K][N] f32 -> Wt [z][N][K] bf16.
// ---------------------------------------------------------------------------
template <int K, int N>
__global__ __launch_bounds__(256)
void transpose_w(const float* __restrict__ W, unsigned short* __restrict__ Wt) {
  const int z = blockIdx.z;
  const int k0 = blockIdx.x * 64, n0 = blockIdx.y * 64;
  __shared__ unsigned short tile[64][66];
  const int t = threadIdx.x;
  {
    const int r = t >> 2, cq = (t & 3) * 16;
    const float* src = W + (size_t)z * K * N + (size_t)(k0 + r) * N + n0 + cq;
#pragma unroll
    for (int i = 0; i < 16; i += 4) {
      f32x4 v = *(const f32x4*)(src + i);
#pragma unroll
      for (int j = 0; j < 4; ++j)
        tile[r][cq + i + j] = (unsigned short)bf16r(v[j]);
    }
  }
  __syncthreads();
  {
    const int n = t >> 2, kc = (t & 3) * 16;
    s16x8 o0, o1;
#pragma unroll
    for (int i = 0; i < 8; ++i) {
      o0[i] = tile[kc + i][n];
      o1[i] = tile[kc + 8 + i][n];
    }
    unsigned short* dst =
        Wt + (size_t)z * N * K + (size_t)(n0 + n) * K + k0 + kc;
    *(s16x8*)dst = o0;
    *(s16x8*)(dst + 8) = o1;
  }
}

// ---------------------------------------------------------------------------
// DETERMINISTIC W2 transpose with ln1-fold. Grid (nblk=32, z=33); each block
// owns a 64-wide N-slice, loops all 16 K-tiles, accumulates gw/bw in
// registers (fixed order), single non-atomic write at end.
//   Wt  = bf16(g_k * W2[k][n]) transposed to [n][k]
//   gw[z][n] = sum_k bf16(g*W);  bw[z][n] = sum_k b_k*bf16(W) + b2[z][n]
// ---------------------------------------------------------------------------
__global__ __launch_bounds__(256)
void transpose_w2g(const float* __restrict__ W, const float* __restrict__ g,
                   const float* __restrict__ bvec, const float* __restrict__ b2,
                   unsigned short* __restrict__ Wt, float* __restrict__ gw,
                   float* __restrict__ bw) {
  constexpr int K = 1024, N = 2048;
  const int z = blockIdx.y;
  const int n0 = blockIdx.x * 64;
  __shared__ unsigned short tileG[64][66];
  __shared__ unsigned short tileW[64][66];
  const int t = threadIdx.x;
  const int rL = t >> 2, cq = (t & 3) * 16;
  const int nS = t >> 2, kc = (t & 3) * 16;
  float gwp = 0.f, bwp = 0.f;

  for (int kt = 0; kt < 16; ++kt) {
    {
      const float gs = g[(size_t)z * K + kt * 64 + rL];
      const float* src =
          W + (size_t)z * K * N + (size_t)(kt * 64 + rL) * N + n0 + cq;
#pragma unroll
      for (int i = 0; i < 16; i += 4) {
        f32x4 v = *(const f32x4*)(src + i);
#pragma unroll
        for (int j = 0; j < 4; ++j) {
          tileW[rL][cq + i + j] = (unsigned short)bf16r(v[j]);
          tileG[rL][cq + i + j] = (unsigned short)bf16r(gs * v[j]);
        }
      }
    }
    __syncthreads();
    {
      s16x8 o0, o1;
#pragma unroll
      for (int i = 0; i < 8; ++i) {
        o0[i] = tileG[kc + i][nS];
        o1[i] = tileG[kc + 8 + i][nS];
      }
#pragma unroll
      for (int i = 0; i < 16; ++i) {
        gwp += bf2f(tileG[kc + i][nS]);
        bwp += bvec[(size_t)z * K + kt * 64 + kc + i] * bf2f(tileW[kc + i][nS]);
      }
      unsigned short* dst =
          Wt + (size_t)z * N * K + (size_t)(n0 + nS) * K + kt * 64 + kc;
      *(s16x8*)dst = o0;
      *(s16x8*)(dst + 8) = o1;
    }
    __syncthreads();
  }
  gwp += __shfl_xor(gwp, 1);
  gwp += __shfl_xor(gwp, 2);
  bwp += __shfl_xor(bwp, 1);
  bwp += __shfl_xor(bwp, 2);
  if ((t & 3) == 0) {
    gw[(size_t)z * N + n0 + nS] = gwp;
    bw[(size_t)z * N + n0 + nS] = bwp + b2[(size_t)z * N + n0 + nS];
  }
}

// ---------------------------------------------------------------------------
// Deterministic row stats (sum, sumsq) of a z-major bf16 buffer.
// One block per row; fixed shuffle-tree order. Used for stats1 (must be
// deterministic: feeds rstd -> bf16 quantization in G2's FUSE epilogue).
// ---------------------------------------------------------------------------
template <int W>
__global__ __launch_bounds__(256)
void stats_w_kernel(const unsigned short* __restrict__ buf,
                    float* __restrict__ stats) {
  constexpr int E = W / 256;
  const int z = blockIdx.x;
  const int b = blockIdx.y;
  const int tid = threadIdx.x;
  const unsigned short* row = buf + ((size_t)z * Bc + b) * W;
  float s = 0.f, s2 = 0.f;
  if constexpr (E == 4) {
    s16x4 t = *(const s16x4*)(row + tid * 4);
#pragma unroll
    for (int i = 0; i < 4; ++i) {
      float v = bf2f(t[i]);
      s += v;
      s2 += v * v;
    }
  } else {
    s16x8 t = *(const s16x8*)(row + tid * 8);
#pragma unroll
    for (int i = 0; i < 8; ++i) {
      float v = bf2f(t[i]);
      s += v;
      s2 += v * v;
    }
  }
#pragma unroll
  for (int o = 32; o > 0; o >>= 1) {
    s += __shfl_xor(s, o);
    s2 += __shfl_xor(s2, o);
  }
  __shared__ float red[2][4];
  const int w = tid >> 6;
  if ((tid & 63) == 0) {
    red[0][w] = s;
    red[1][w] = s2;
  }
  __syncthreads();
  if (tid == 0) {
    stats[((size_t)z * Bc + b) * 2 + 0] =
        red[0][0] + red[0][1] + red[0][2] + red[0][3];
    stats[((size_t)z * Bc + b) * 2 + 1] =
        red[1][0] + red[1][1] + red[1][2] + red[1][3];
  }
}

// ---------------------------------------------------------------------------
// 8-phase counted-vmcnt GEMM (r7/r9 schedule, paired-row 128B LDS, 0
// conflicts). z-major A: [z][2048][K]. GELU epilogue or FUSE (folded ln1).
// STATS: per-row sum/sumsq atomics into `stats` (z-major). Safe here because
// stats2 feeds only f32 math in attn (no bf16 quantization downstream);
// this exact mechanism passed the determinism tripwire in r5/r6/r7.
// ---------------------------------------------------------------------------
template <int K, int N, int NBN, int GELU, int FUSE, int STATS>
__global__ __launch_bounds__(512, 2)
void gemm8ph(const unsigned short* __restrict__ A,
             const unsigned short* __restrict__ Wt,
             const float* __restrict__ bias,
             unsigned short* __restrict__ outbuf,
             const float* __restrict__ gw, const float* __restrict__ bw,
             const float* __restrict__ stats1, float* __restrict__ stats2) {
  constexpr int NT = K / 64;
  constexpr int NIT = NT / 2;
  constexpr int NBM = 8;
  extern __shared__ __align__(16) char smem[];

  constexpr int nwg = 33 * NBM * NBN;
  constexpr int q = nwg >> 3, r = nwg & 7;
  const int orig = blockIdx.x;
  const int xcd = orig & 7;
  const int wgid =
      ((xcd < r) ? xcd * (q + 1) : r * (q + 1) + (xcd - r) * q) + (orig >> 3);
  const int z = wgid / (NBM * NBN);
  const int rem = wgid - z * (NBM * NBN);
  const int bm = rem / NBN, bn = rem - bm * NBN;

  const int tid = threadIdx.x, lane = tid & 63, wv = tid >> 6;
  const int wm = wv >> 2, wn = wv & 3;
  const int wr = wm * 128, wc = wn * 64;
  const int l15 = lane & 15, l4 = lane >> 4;

  f32x4 acc[8][4];
#pragma unroll
  for (int m = 0; m < 8; ++m)
#pragma unroll
    for (int n = 0; n < 4; ++n) {
      acc[m][n][0] = 0.f; acc[m][n][1] = 0.f;
      acc[m][n][2] = 0.f; acc[m][n][3] = 0.f;
    }

  const unsigned short* aRow[2];
  const unsigned short* bRow[2];
  {
    const unsigned short* Bbase = Wt + (size_t)z * N * K;
#pragma unroll
    for (int c = 0; c < 2; ++c) {
      const int rprime = wv * 16 + c * 8 + (lane >> 3);
      const int row = 2 * rprime + ((lane >> 2) & 1);
      const int chunk = (lane & 3) ^ (rprime & 3);
      aRow[c] = A + ((size_t)z * Bc + bm * 256 + row) * K + chunk * 8;
      bRow[c] = Bbase + (size_t)(bn * 256 + row) * K + chunk * 8;
    }
  }

  auto STAGE_A = [&](int t, int kh) {
    char* dst = smem + (t & 1) * 65536 + kh * 16384 + wv * 2048;
    const int ko = t * 64 + kh * 32;
#pragma unroll
    for (int c = 0; c < 2; ++c) gl_lds16(aRow[c] + ko, dst + c * 1024);
  };
  auto STAGE_B = [&](int t, int kh) {
    char* dst = smem + (t & 1) * 65536 + 32768 + kh * 16384 + wv * 2048;
    const int ko = t * 64 + kh * 32;
#pragma unroll
    for (int c = 0; c < 2; ++c) gl_lds16(bRow[c] + ko, dst + c * 1024);
  };
  s16x8 afr[4], bfr[4];
  auto LDA = [&](int d, int kh, int mh) {
#pragma unroll
    for (int m = 0; m < 4; ++m) {
      const int row = wr + (mh * 4 + m) * 16 + l15;
      const int rp = row >> 1;
      afr[m] = *(const s16x8*)(smem + d * 65536 + kh * 16384 + rp * 128 +
                               (row & 1) * 64 + ((l4 ^ (rp & 3)) << 4));
    }
  };
  auto LDB = [&](int d, int kh) {
#pragma unroll
    for (int n = 0; n < 4; ++n) {
      const int row = wc + n * 16 + l15;
      const int rp = row >> 1;
      bfr[n] = *(const s16x8*)(smem + d * 65536 + 32768 + kh * 16384 +
                               rp * 128 + (row & 1) * 64 +
                               ((l4 ^ (rp & 3)) << 4));
    }
  };

#define MFMA16(MH)                                                          \
  {                                                                         \
    __builtin_amdgcn_s_setprio(1);                                          \
    _Pragma("unroll") for (int m_ = 0; m_ < 4; ++m_) {                      \
      _Pragma("unroll") for (int n_ = 0; n_ < 4; ++n_) {                    \
        acc[(MH) * 4 + m_][n_] = __builtin_amdgcn_mfma_f32_16x16x32_bf16(   \
            afr[m_], bfr[n_], acc[(MH) * 4 + m_][n_], 0, 0, 0);             \
      }                                                                     \
    }                                                                       \
    __builtin_amdgcn_s_setprio(0);                                          \
  }

  STAGE_A(0, 0); STAGE_B(0, 0); STAGE_A(0, 1); STAGE_B(0, 1);
  STAGE_A(1, 0); STAGE_B(1, 0);
  VM4();
  BARw();

  for (int i = 0; i < NIT; ++i) {
    const int t0 = 2 * i, t1 = 2 * i + 1;
    LDA(0, 0, 0); LDB(0, 0);
    STAGE_A(t1, 1);
    BARw(); MFMA16(0); BARw();
    LDA(0, 0, 1);
    STAGE_B(t1, 1);
    BARw(); MFMA16(1); BARw();
    LDA(0, 1, 0); LDB(0, 1);
    if (t0 + 2 < NT) STAGE_A(t0 + 2, 0);
    BARw(); MFMA16(0); BARw();
    LDA(0, 1, 1);
    if (t0 + 2 < NT) STAGE_B(t0 + 2, 0);
    BARw(); MFMA16(1);
    VM4();
    BARw();
    LDA(1, 0, 0); LDB(1, 0);
    if (t0 + 2 < NT) STAGE_A(t0 + 2, 1);
    BARw(); MFMA16(0); BARw();
    LDA(1, 0, 1);
    if (t0 + 2 < NT) STAGE_B(t0 + 2, 1);
    BARw(); MFMA16(1); BARw();
    LDA(1, 1, 0); LDB(1, 1);
    if (t0 + 3 < NT) STAGE_A(t0 + 3, 0);
    BARw(); MFMA16(0); BARw();
    LDA(1, 1, 1);
    if (t0 + 3 < NT) STAGE_B(t0 + 3, 0);
    BARw(); MFMA16(1);
    VM4();
    BARw();
  }
#undef MFMA16

  float bsv[4], gwv[4], bwv[4];
#pragma unroll
  for (int n = 0; n < 4; ++n) {
    const int col = bn * 256 + wc + n * 16 + l15;
    if constexpr (FUSE) {
      gwv[n] = gw[(size_t)z * N + col];
      bwv[n] = bw[(size_t)z * N + col];
    } else {
      bsv[n] = bias[(size_t)z * N + col];
    }
  }

#pragma unroll
  for (int m = 0; m < 8; ++m) {
#pragma unroll
    for (int j = 0; j < 4; ++j) {
      const int grow = bm * 256 + wr + m * 16 + l4 * 4 + j;
      float mu = 0.f, rstd = 0.f;
      if constexpr (FUSE) {
        const float st0 = stats1[((size_t)z * Bc + grow) * 2 + 0];
        const float st1 = stats1[((size_t)z * Bc + grow) * 2 + 1];
        mu = st0 * (1.0f / K);
        const float var = st1 * (1.0f / K) - mu * mu;
        rstd = rsqrtf(var + 1e-5f);
      }
      float s1 = 0.f, s2 = 0.f;
#pragma unroll
      for (int n = 0; n < 4; ++n) {
        const int col = bn * 256 + wc + n * 16 + l15;
        float v;
        if constexpr (FUSE) {
          v = rstd * acc[m][n][j] - (rstd * mu) * gwv[n] + bwv[n];
        } else {
          v = acc[m][n][j] + bsv[n];
        }
        if constexpr (GELU) v = 0.5f * v * (1.0f + erff(v * 0.70710678118f));
        outbuf[((size_t)z * Bc + grow) * N + col] = (unsigned short)bf16r(v);
        if constexpr (STATS) {
          // accumulate the bf16-ROUNDED value (matches what attn reads)
          const float vr = bf2f(bf16r(v));
          s1 += vr;
          s2 += vr * vr;
        }
      }
      if constexpr (STATS) {
#pragma unroll
        for (int o = 1; o < 16; o <<= 1) {
          s1 += __shfl_xor(s1, o);
          s2 += __shfl_xor(s2, o);
        }
        if (l15 == 0) {
          atomicAdd(&stats2[((size_t)z * Bc + grow) * 2 + 0], s1);
          atomicAdd(&stats2[((size_t)z * Bc + grow) * 2 + 1], s2);
        }
      }
    }
  }
}

// ---------------------------------------------------------------------------
// Old-style fused GEMM (reg-staged). Split-precision query path (SPLITQ=1)
// and full fallback path. MODE1/MODE2 outputs are z-major.
// ---------------------------------------------------------------------------
template <int MODE, int SPLITQ>
__global__ __launch_bounds__(256, 2)
void gemm_fused(const float* __restrict__ x,
                const unsigned short* __restrict__ hbuf,
                const float* __restrict__ hqF,
                const float* __restrict__ Wmain, const float* __restrict__ Wq,
                const float* __restrict__ bmain, const float* __restrict__ bq,
                unsigned short* __restrict__ outH, float* __restrict__ outHq,
                unsigned short* __restrict__ outV, float* __restrict__ outQ) {
  constexpr int K = (MODE == 1) ? 2048 : 1024;
  constexpr int N = (MODE == 1) ? 1024 : 2048;
  constexpr int BK = 32;
  constexpr int NT = K / BK;

  const int z = blockIdx.z;
  const int bm = blockIdx.x;
  const int bn = blockIdx.y;
  const int tid = threadIdx.x;
  const int lane = tid & 63;
  const int wid = tid >> 6;
  const int wr = (wid >> 1) * 64;
  const int wc = (wid & 1) * 64;
  const int l15 = lane & 15;
  const int kb = lane >> 4;

  const float* Bp = SPLITQ ? Wq : (Wmain + (size_t)z * K * N);

  __shared__ short Als[1 + SPLITQ][128][32];
  __shared__ short Bls[1 + SPLITQ][128][32];

  const f32x4 vzero = {0.f, 0.f, 0.f, 0.f};
  f32x4 acc[4][4];
#pragma unroll
  for (int m = 0; m < 4; ++m)
#pragma unroll
    for (int n = 0; n < 4; ++n) acc[m][n] = vzero;

  const int ar = tid >> 1;
  const int ak = (tid & 1) * 16;
  const int grow = bm * 128 + ar;

  const float* ApF = nullptr;
  const unsigned short* ApH = nullptr;
  if constexpr (MODE == 1) {
    const int lsel = SPLITQ ? (Lc - 1) : z;
    ApF = x + (size_t)grow * (Lc * Dc) + (size_t)lsel * Dc + ak;
  } else if constexpr (SPLITQ == 1) {
    ApF = hqF + (size_t)grow * DBc + ak;
  } else {
    ApH = hbuf + ((size_t)z * Bc + grow) * DBc + ak;
  }

  const int bnL = tid & 127;
  const int bj = tid >> 7;
  const int c0 = ((bnL >> 1) & 3) ^ bj;
  const int kc0 = c0 * 8;
  const int kc1 = (c0 ^ 2) * 8;
  const float* Bcol = Bp + (size_t)bn * 128 + bnL;

  float aF[16];
  s16x8 aH0, aH1;
  float bF[16];

  auto loadA = [&](int kt) {
    if constexpr (MODE == 2 && SPLITQ == 0) {
      const unsigned short* p = ApH + kt * BK;
      aH0 = *(const s16x8*)p;
      aH1 = *(const s16x8*)(p + 8);
    } else {
      const float* p = ApF + kt * BK;
#pragma unroll
      for (int i = 0; i < 4; ++i) {
        f32x4 t = *(const f32x4*)(p + i * 4);
#pragma unroll
        for (int j = 0; j < 4; ++j) aF[i * 4 + j] = t[j];
      }
    }
  };
  auto loadB = [&](int kt) {
    const float* p0 = Bcol + (size_t)(kt * BK + kc0) * N;
    const float* p1 = Bcol + (size_t)(kt * BK + kc1) * N;
#pragma unroll
    for (int i = 0; i < 8; ++i) bF[i] = p0[(size_t)i * N];
#pragma unroll
    for (int i = 0; i < 8; ++i) bF[8 + i] = p1[(size_t)i * N];
  };
  auto writeLDS = [&]() {
    if constexpr (MODE == 2 && SPLITQ == 0) {
      *(s16x8*)&Als[0][ar][ak] = aH0;
      *(s16x8*)&Als[0][ar][ak + 8] = aH1;
    } else if constexpr (SPLITQ == 0) {
      *(s16x8*)&Als[0][ar][ak] = pack8(aF);
      *(s16x8*)&Als[0][ar][ak + 8] = pack8(aF + 8);
    } else {
      s16x8 h0, l0, h1, l1;
      split8(aF, h0, l0);
      split8(aF + 8, h1, l1);
      *(s16x8*)&Als[0][ar][ak] = h0;
      *(s16x8*)&Als[1][ar][ak] = l0;
      *(s16x8*)&Als[0][ar][ak + 8] = h1;
      *(s16x8*)&Als[1][ar][ak + 8] = l1;
    }
    if constexpr (SPLITQ == 0) {
      *(s16x8*)&Bls[0][bnL][kc0] = pack8(bF);
      *(s16x8*)&Bls[0][bnL][kc1] = pack8(bF + 8);
    } else {
      s16x8 h0, l0, h1, l1;
      split8(bF, h0, l0);
      split8(bF + 8, h1, l1);
      *(s16x8*)&Bls[0][bnL][kc0] = h0;
      *(s16x8*)&Bls[1][bnL][kc0] = l0;
      *(s16x8*)&Bls[0][bnL][kc1] = h1;
      *(s16x8*)&Bls[1][bnL][kc1] = l1;
    }
  };

  loadA(0);
  loadB(0);
  for (int kt = 0; kt < NT; ++kt) {
    __syncthreads();
    writeLDS();
    if (kt + 1 < NT) {
      loadA(kt + 1);
      loadB(kt + 1);
    }
    __syncthreads();
    s16x8 af[4], bfv[4];
#pragma unroll
    for (int m = 0; m < 4; ++m)
      af[m] = *(const s16x8*)&Als[0][wr + m * 16 + l15][kb * 8];
#pragma unroll
    for (int n = 0; n < 4; ++n)
      bfv[n] = *(const s16x8*)&Bls[0][wc + n * 16 + l15][kb * 8];
    if constexpr (SPLITQ == 1) {
      s16x8 afl[4], bfl[4];
#pragma unroll
      for (int m = 0; m < 4; ++m)
        afl[m] = *(const s16x8*)&Als[1][wr + m * 16 + l15][kb * 8];
#pragma unroll
      for (int n = 0; n < 4; ++n)
        bfl[n] = *(const s16x8*)&Bls[1][wc + n * 16 + l15][kb * 8];
#pragma unroll
      for (int m = 0; m < 4; ++m)
#pragma unroll
        for (int n = 0; n < 4; ++n) {
          acc[m][n] = __builtin_amdgcn_mfma_f32_16x16x32_bf16(
              af[m], bfv[n], acc[m][n], 0, 0, 0);
          acc[m][n] = __builtin_amdgcn_mfma_f32_16x16x32_bf16(
              af[m], bfl[n], acc[m][n], 0, 0, 0);
          acc[m][n] = __builtin_amdgcn_mfma_f32_16x16x32_bf16(
              afl[m], bfv[n], acc[m][n], 0, 0, 0);
        }
    } else {
#pragma unroll
      for (int m = 0; m < 4; ++m)
#pragma unroll
        for (int n = 0; n < 4; ++n)
          acc[m][n] = __builtin_amdgcn_mfma_f32_16x16x32_bf16(
              af[m], bfv[n], acc[m][n], 0, 0, 0);
    }
  }

  const float* biasP = SPLITQ ? bq : (bmain + (size_t)z * N);
#pragma unroll
  for (int m = 0; m < 4; ++m) {
    const int r0 = bm * 128 + wr + m * 16 + kb * 4;
#pragma unroll
    for (int n = 0; n < 4; ++n) {
      const int col = bn * 128 + wc + n * 16 + l15;
      const float bs = biasP[col];
#pragma unroll
      for (int j = 0; j < 4; ++j) {
        const int r = r0 + j;
        const float v = acc[m][n][j] + bs;
        if constexpr (MODE == 1 && SPLITQ == 0) {
          const float g = 0.5f * v * (1.0f + erff(v * 0.70710678118f));
          outH[((size_t)z * Bc + r) * DBc + col] = (unsigned short)bf16r(g);
        } else if constexpr (MODE == 1 && SPLITQ == 1) {
          const float g = 0.5f * v * (1.0f + erff(v * 0.70710678118f));
          outHq[(size_t)r * DBc + col] = g;
        } else if constexpr (MODE == 2 && SPLITQ == 0) {
          outV[((size_t)z * Bc + r) * Dc + col] = (unsigned short)bf16r(v);
        } else {
          const float zl =
              x[(size_t)r * (Lc * Dc) + (size_t)(Lc - 1) * Dc + col];
          const float t = zl + v;
          outQ[(size_t)r * Dc + col] = (t > 0.f) ? (1.f + t) : __expf(t);
        }
      }
    }
  }
}

// ---------------------------------------------------------------------------
// Row LayerNorm over last dim W, in place, z-major buffer (fallback only).
// ---------------------------------------------------------------------------
template <int W>
__global__ __launch_bounds__(256)
void ln_kernel(unsigned short* __restrict__ buf, const float* __restrict__ gmain,
               const float* __restrict__ bmain) {
  constexpr int E = W / 256;
  const int z = blockIdx.x;
  const int b = blockIdx.y;
  const int tid = threadIdx.x;
  unsigned short* row = buf + ((size_t)z * Bc + b) * W;
  float v[E];
  if constexpr (E == 4) {
    s16x4 t = *(const s16x4*)(row + tid * 4);
#pragma unroll
    for (int i = 0; i < 4; ++i) v[i] = bf2f(t[i]);
  } else {
    s16x8 t = *(const s16x8*)(row + tid * 8);
#pragma unroll
    for (int i = 0; i < 8; ++i) v[i] = bf2f(t[i]);
  }
  float s = 0.f, s2 = 0.f;
#pragma unroll
  for (int i = 0; i < E; ++i) {
    s += v[i];
    s2 += v[i] * v[i];
  }
#pragma unroll
  for (int o = 32; o > 0; o >>= 1) {
    s += __shfl_xor(s, o);
    s2 += __shfl_xor(s2, o);
  }
  __shared__ float red[2][4];
  const int w = tid >> 6;
  if ((tid & 63) == 0) {
    red[0][w] = s;
    red[1][w] = s2;
  }
  __syncthreads();
  s = red[0][0] + red[0][1] + red[0][2] + red[0][3];
  s2 = red[1][0] + red[1][1] + red[1][2] + red[1][3];
  const float mu = s * (1.0f / W);
  const float var = s2 * (1.0f / W) - mu * mu;
  const float rstd = rsqrtf(var + 1e-5f);
  const float* G = gmain + (size_t)z * W;
  const float* Bt = bmain + (size_t)z * W;
  if constexpr (E == 4) {
    f32x4 gv = *(const f32x4*)(G + tid * 4);
    f32x4 bv = *(const f32x4*)(Bt + tid * 4);
    s16x4 o;
#pragma unroll
    for (int i = 0; i < 4; ++i)
      o[i] = bf16r((v[i] - mu) * rstd * gv[i] + bv[i]);
    *(s16x4*)(row + tid * 4) = o;
  } else {
    f32x4 g0 = *(const f32x4*)(G + tid * 8);
    f32x4 g1 = *(const f32x4*)(G + tid * 8 + 4);
    f32x4 b0 = *(const f32x4*)(Bt + tid * 8);
    f32x4 b1 = *(const f32x4*)(Bt + tid * 8 + 4);
    s16x8 o;
#pragma unroll
    for (int i = 0; i < 4; ++i) {
      o[i] = bf16r((v[i] - mu) * rstd * g0[i] + b0[i]);
      o[i + 4] = bf16r((v[i + 4] - mu) * rstd * g1[i] + b1[i]);
    }
    *(s16x8*)(row + tid * 8) = o;
  }
}

// ---------------------------------------------------------------------------
// f32 LayerNorm for hq (2048 rows x 1024), in place.
// ---------------------------------------------------------------------------
__global__ __launch_bounds__(256)
void ln_f32_kernel(float* __restrict__ buf, const float* __restrict__ g,
                   const float* __restrict__ bb) {
  const int r = blockIdx.x;
  const int tid = threadIdx.x;
  float* row = buf + (size_t)r * DBc;
  f32x4 v = *(const f32x4*)(row + tid * 4);
  float s = 0.f, s2 = 0.f;
#pragma unroll
  for (int i = 0; i < 4; ++i) {
    s += v[i];
    s2 += v[i] * v[i];
  }
#pragma unroll
  for (int o = 32; o > 0; o >>= 1) {
    s += __shfl_xor(s, o);
    s2 += __shfl_xor(s2, o);
  }
  __shared__ float red[2][4];
  const int w = tid >> 6;
  if ((tid & 63) == 0) {
    red[0][w] = s;
    red[1][w] = s2;
  }
  __syncthreads();
  s = red[0][0] + red[0][1] + red[0][2] + red[0][3];
  s2 = red[1][0] + red[1][1] + red[1][2] + red[1][3];
  const float mu = s * (1.0f / DBc);
  const float var = s2 * (1.0f / DBc) - mu * mu;
  const float rstd = rsqrtf(var + 1e-5f);
  f32x4 gv = *(const f32x4*)(g + tid * 4);
  f32x4 bv = *(const f32x4*)(bb + tid * 4);
  f32x4 o;
#pragma unroll
  for (int i = 0; i < 4; ++i) o[i] = (v[i] - mu) * rstd * gv[i] + bv[i];
  *(f32x4*)(row + tid * 4) = o;
}

// ---------------------------------------------------------------------------
// Final attention with fused ln2, z-major vals/stats (r9-proven form).
// ---------------------------------------------------------------------------
__global__ __launch_bounds__(256)
void attn_kernel(const float* __restrict__ x, const float* __restrict__ query,
                 const float* __restrict__ keys,
                 const unsigned short* __restrict__ vals,
                 const float* __restrict__ stats, const float* __restrict__ g2,
                 const float* __restrict__ b2ln, float* __restrict__ out) {
  const int b = blockIdx.x;
  const int tid = threadIdx.x;
  const int d0 = tid * 8;

  float qv[8];
  {
    f32x4 t0 = *(const f32x4*)(query + (size_t)b * Dc + d0);
    f32x4 t1 = *(const f32x4*)(query + (size_t)b * Dc + d0 + 4);
#pragma unroll
    for (int i = 0; i < 4; ++i) {
      qv[i] = t0[i];
      qv[i + 4] = t1[i];
    }
  }
  float s[33];
#pragma unroll
  for (int l = 0; l < 33; ++l) {
    const float* kp = keys + (size_t)l * Dc + d0;
    f32x4 k0 = *(const f32x4*)kp;
    f32x4 k1 = *(const f32x4*)(kp + 4);
    float t = 0.f;
#pragma unroll
    for (int i = 0; i < 4; ++i) t += qv[i] * k0[i] + qv[i + 4] * k1[i];
    s[l] = t;
  }
#pragma unroll
  for (int l = 0; l < 33; ++l) {
    float v = s[l];
#pragma unroll
    for (int o = 32; o > 0; o >>= 1) v += __shfl_xor(v, o);
    s[l] = v;
  }
  __shared__ float sred[4][33];
  __shared__ float sl[33];
  const int w = tid >> 6;
  if ((tid & 63) == 0) {
#pragma unroll
    for (int l = 0; l < 33; ++l) sred[w][l] = s[l];
  }
  __syncthreads();
  if (tid < 33)
    sl[tid] = sred[0][tid] + sred[1][tid] + sred[2][tid] + sred[3][tid];
  __syncthreads();

  float m = -1e30f;
#pragma unroll
  for (int l = 0; l < 33; ++l) m = fmaxf(m, sl[l]);
  float p[33];
  float sum = 0.f;
#pragma unroll
  for (int l = 0; l < 33; ++l) {
    p[l] = __expf(sl[l] - m);
    sum += p[l];
  }
  const float inv = 1.0f / sum;

  float acc8[8];
  {
    const float* zl = x + (size_t)b * (Lc * Dc) + (size_t)(Lc - 1) * Dc + d0;
    f32x4 z0 = *(const f32x4*)zl;
    f32x4 z1 = *(const f32x4*)(zl + 4);
#pragma unroll
    for (int i = 0; i < 4; ++i) {
      acc8[i] = z0[i];
      acc8[i + 4] = z1[i];
    }
  }
#pragma unroll
  for (int l = 0; l < 33; ++l) {
    const float st0 = stats[((size_t)l * Bc + b) * 2 + 0];
    const float st1 = stats[((size_t)l * Bc + b) * 2 + 1];
    const float mu = st0 * (1.0f / Dc);
    const float var = st1 * (1.0f / Dc) - mu * mu;
    const float rstd = rsqrtf(var + 1e-5f);
    const float a = p[l] * inv;
    s16x8 vv = *(const s16x8*)(vals + ((size_t)l * Bc + b) * Dc + d0);
    const float* gp = g2 + (size_t)l * Dc + d0;
    const float* bp = b2ln + (size_t)l * Dc + d0;
    f32x4 g0 = *(const f32x4*)gp, g1 = *(const f32x4*)(gp + 4);
    f32x4 b0 = *(const f32x4*)bp, b1 = *(const f32x4*)(bp + 4);
#pragma unroll
    for (int i = 0; i < 4; ++i) {
      acc8[i] += a * ((bf2f(vv[i]) - mu) * rstd * g0[i] + b0[i]);
      acc8[i + 4] += a * ((bf2f(vv[i + 4]) - mu) * rstd * g1[i] + b1[i]);
    }
  }
  f32x4 o0, o1;
#pragma unroll
  for (int i = 0; i < 4; ++i) {
    o0[i] = acc8[i];
    o1[i] = acc8[i + 4];
  }
  *(f32x4*)(out + (size_t)b * Dc + d0) = o0;
  *(f32x4*)(out + (size_t)b * Dc + d0 + 4) = o1;
}

// ---------------------------------------------------------------------------
extern "C" void kernel_launch(void* const* d_in, const int* in_sizes, int n_in,
                              void* d_out, int out_size, void* d_ws,
                              size_t ws_size, hipStream_t stream) {
  const float* x = (const float*)d_in[0];
  const float* pe = (const float*)d_in[1];
  const float* Wk = (const float*)d_in[2];
  const float* W1 = (const float*)d_in[3];
  const float* b1 = (const float*)d_in[4];
  const float* ln1g = (const float*)d_in[5];
  const float* ln1b = (const float*)d_in[6];
  const float* W2 = (const float*)d_in[7];
  const float* b2 = (const float*)d_in[8];
  const float* ln2g = (const float*)d_in[9];
  const float* ln2b = (const float*)d_in[10];
  const float* Wq1 = (const float*)d_in[11];
  const float* bq1 = (const float*)d_in[12];
  const float* lnqg = (const float*)d_in[13];
  const float* lnqb = (const float*)d_in[14];
  const float* Wq2 = (const float*)d_in[15];
  const float* bq2 = (const float*)d_in[16];
  float* out = (float*)d_out;
  char* ws = (char*)d_ws;

  // ws layout (bytes), lifetime-aliased (r9 layout):
  //   keys   @ 0            (270,336)
  //   query  @ 270,336      (16,777,216)
  //   hq     @ 17,047,552   (8,388,608)
  //   stats1 @ 25,436,160   (540,672)   h row stats (deterministic -> FUSE)
  //   stats2 @ 25,976,832   (540,672)   vals row stats (G2 atomics -> attn)
  //   gw     @ 26,517,504   (270,336)
  //   bw     @ 26,787,840   (270,336)
  //   h      @ 27,058,176   (138,412,032)  bf16 [33][2048][1024] z-major
  //   xbf    @ 165,470,208  (276,824,064)  cvt->G1
  //   vals   @ 165,470,208  (ALIAS xbf: G2->attn)
  //   W1t    @ 442,294,272  (138,412,032)  t1->G1
  //   W2gt   @ 442,294,272  (ALIAS: t2g->G2)  -> end 580,706,304
  float* keysP = (float*)(ws);
  float* queryP = (float*)(ws + 270336);
  float* hqP = (float*)(ws + 17047552);
  float* stats1P = (float*)(ws + 25436160);
  float* stats2P = (float*)(ws + 25976832);
  float* gwP = (float*)(ws + 26517504);
  float* bwP = (float*)(ws + 26787840);
  unsigned short* hP = (unsigned short*)(ws + 27058176);
  unsigned short* xbfP = (unsigned short*)(ws + 165470208);
  unsigned short* valsP = (unsigned short*)(ws + 165470208);
  unsigned short* W1tP = (unsigned short*)(ws + 442294272);
  unsigned short* W2gtP = (unsigned short*)(ws + 442294272);

  const bool fast = (ws_size >= 580706304ull);
  bool use8 = fast;
  if (fast) {
    if (hipFuncSetAttribute(
            reinterpret_cast<const void*>(&gemm8ph<2048, 1024, 4, 1, 0, 0>),
            hipFuncAttributeMaxDynamicSharedMemorySize, 131072) != hipSuccess)
      use8 = false;
    if (hipFuncSetAttribute(
            reinterpret_cast<const void*>(&gemm8ph<1024, 2048, 8, 0, 1, 1>),
            hipFuncAttributeMaxDynamicSharedMemorySize, 131072) != hipSuccess)
      use8 = false;
  }

  keys_kernel<<<dim3(33, 8), 256, 0, stream>>>(pe, Wk, keysP);

  gemm_fused<1, 1><<<dim3(16, 8, 1), 256, 0, stream>>>(
      x, nullptr, nullptr, nullptr, Wq1, nullptr, bq1, nullptr, hqP, nullptr,
      nullptr);

  if (use8) {
    cvt_perm_kernel<<<dim3(2048, 33), 256, 0, stream>>>(x, xbfP);
    transpose_w<2048, 1024><<<dim3(32, 16, 33), 256, 0, stream>>>(W1, W1tP);
    gemm8ph<2048, 1024, 4, 1, 0, 0>
        <<<dim3(33 * 8 * 4), 512, 131072, stream>>>(xbfP, W1tP, b1, hP,
                                                    nullptr, nullptr, nullptr,
                                                    nullptr);
    stats_w_kernel<1024><<<dim3(33, 2048), 256, 0, stream>>>(hP, stats1P);
    ln_f32_kernel<<<dim3(2048), 256, 0, stream>>>(hqP, lnqg, lnqb);
    transpose_w2g<<<dim3(32, 33), 256, 0, stream>>>(W2, ln1g, ln1b, b2, W2gtP,
                                                    gwP, bwP);
    hipMemsetAsync(stats2P, 0, 540672, stream);
    gemm8ph<1024, 2048, 8, 0, 1, 1>
        <<<dim3(33 * 8 * 8), 512, 131072, stream>>>(hP, W2gtP, nullptr, valsP,
                                                    gwP, bwP, stats1P,
                                                    stats2P);
  } else {
    gemm_fused<1, 0><<<dim3(16, 8, 33), 256, 0, stream>>>(
        x, nullptr, nullptr, W1, nullptr, b1, nullptr, hP, nullptr, nullptr,
        nullptr);
    ln_kernel<1024><<<dim3(33, 2048), 256, 0, stream>>>(hP, ln1g, ln1b);
    ln_f32_kernel<<<dim3(2048), 256, 0, stream>>>(hqP, lnqg, lnqb);
    gemm_fused<2, 0><<<dim3(16, 16, 33), 256, 0, stream>>>(
        x, hP, nullptr, W2, nullptr, b2, nullptr, nullptr, nullptr, valsP,
        nullptr);
    stats_w_kernel<2048><<<dim3(33, 2048), 256, 0, stream>>>(valsP, stats2P);
  }

  gemm_fused<2, 1><<<dim3(16, 16, 1), 256, 0, stream>>>(
      x, nullptr, hqP, nullptr, Wq2, nullptr, bq2, nullptr, nullptr, nullptr,
      queryP);

  attn_kernel<<<dim3(2048), 256, 0, stream>>>(x, queryP, keysP, valsP,
                                              stats2P, ln2g, ln2b, out);
}

// Round 13
// 1529.312 us; speedup vs baseline: 1.1547x; 1.1547x over previous
//
#include <hip/hip_runtime.h>
#include <cstddef>
#include <cstdint>

#define Lc 33
#define Dc 2048
#define DBc 1024
#define Pc 24
#define Bc 2048

typedef __attribute__((ext_vector_type(4))) float f32x4;
typedef __attribute__((ext_vector_type(8))) short s16x8;
typedef __attribute__((ext_vector_type(4))) short s16x4;

__device__ __forceinline__ short bf16r(float f) {
  unsigned u = __float_as_uint(f);
  u = (u + 0x7fffu + ((u >> 16) & 1u)) >> 16;
  return (short)u;
}
__device__ __forceinline__ float bf2f(short s) {
  return __uint_as_float(((unsigned)(unsigned short)s) << 16);
}
__device__ __forceinline__ s16x8 pack8(const float* f) {
  s16x8 r;
#pragma unroll
  for (int i = 0; i < 8; ++i) r[i] = bf16r(f[i]);
  return r;
}
__device__ __forceinline__ void split8(const float* f, s16x8& hi, s16x8& lo) {
#pragma unroll
  for (int i = 0; i < 8; ++i) {
    short h = bf16r(f[i]);
    hi[i] = h;
    lo[i] = bf16r(f[i] - bf2f(h));
  }
}
__device__ __forceinline__ void gl_lds16(const void* g, void* l) {
  __builtin_amdgcn_global_load_lds(
      (const __attribute__((address_space(1))) unsigned int*)g,
      (__attribute__((address_space(3))) unsigned int*)l, 16, 0, 0);
}

#define BARw() __builtin_amdgcn_s_barrier()
#define VM4() asm volatile("s_waitcnt vmcnt(4)" ::: "memory")

// ---------------------------------------------------------------------------
// x [b][l][k] f32 -> xbf [z][b][k] bf16 (permuting convert)
// ---------------------------------------------------------------------------
__global__ __launch_bounds__(256)
void cvt_perm_kernel(const float* __restrict__ in,
                     unsigned short* __restrict__ outp) {
  const int row = blockIdx.x, z = blockIdx.y;
  const int k0 = threadIdx.x * 8;
  const float* src = in + ((size_t)row * Lc + z) * Dc + k0;
  f32x4 a = *(const f32x4*)(src);
  f32x4 b = *(const f32x4*)(src + 4);
  float f[8] = {a[0], a[1], a[2], a[3], b[0], b[1], b[2], b[3]};
  *(s16x8*)(outp + ((size_t)z * Bc + row) * Dc + k0) = pack8(f);
}

// ---------------------------------------------------------------------------
// keys = pos_emb @ Wk   (33 x 2048, K=24)
// ---------------------------------------------------------------------------
__global__ __launch_bounds__(256)
void keys_kernel(const float* __restrict__ pe, const float* __restrict__ Wk,
                 float* __restrict__ keys) {
  const int l = blockIdx.x;
  const int d = blockIdx.y * 256 + threadIdx.x;
  float s = 0.f;
#pragma unroll
  for (int p = 0; p < Pc; ++p) s += pe[l * Pc + p] * Wk[(size_t)p * Dc + d];
  keys[(size_t)l * Dc + d] = s;
}

// ---------------------------------------------------------------------------
// Transpose + bf16-convert W1: [z][K][N] f32 -> Wt [z][N][K] bf16.
// ---------------------------------------------------------------------------
template <int K, int N>
__global__ __launch_bounds__(256)
void transpose_w(const float* __restrict__ W, unsigned short* __restrict__ Wt) {
  const int z = blockIdx.z;
  const int k0 = blockIdx.x * 64, n0 = blockIdx.y * 64;
  __shared__ unsigned short tile[64][66];
  const int t = threadIdx.x;
  {
    const int r = t >> 2, cq = (t & 3) * 16;
    const float* src = W + (size_t)z * K * N + (size_t)(k0 + r) * N + n0 + cq;
#pragma unroll
    for (int i = 0; i < 16; i += 4) {
      f32x4 v = *(const f32x4*)(src + i);
#pragma unroll
      for (int j = 0; j < 4; ++j)
        tile[r][cq + i + j] = (unsigned short)bf16r(v[j]);
    }
  }
  __syncthreads();
  {
    const int n = t >> 2, kc = (t & 3) * 16;
    s16x8 o0, o1;
#pragma unroll
    for (int i = 0; i < 8; ++i) {
      o0[i] = tile[kc + i][n];
      o1[i] = tile[kc + 8 + i][n];
    }
    unsigned short* dst =
        Wt + (size_t)z * N * K + (size_t)(n0 + n) * K + k0 + kc;
    *(s16x8*)dst = o0;
    *(s16x8*)(dst + 8) = o1;
  }
}

// ---------------------------------------------------------------------------
// DETERMINISTIC W2 transpose with ln1-fold. Grid (nblk=32, z=33); each block
// owns a 64-wide N-slice, loops all 16 K-tiles, accumulates gw/bw in
// registers (fixed order), single non-atomic write at end.
//   Wt  = bf16(g_k * W2[k][n]) transposed to [n][k]
//   gw[z][n] = sum_k bf16(g*W);  bw[z][n] = sum_k b_k*bf16(W) + b2[z][n]
// ---------------------------------------------------------------------------
__global__ __launch_bounds__(256)
void transpose_w2g(const float* __restrict__ W, const float* __restrict__ g,
                   const float* __restrict__ bvec, const float* __restrict__ b2,
                   unsigned short* __restrict__ Wt, float* __restrict__ gw,
                   float* __restrict__ bw) {
  constexpr int K = 1024, N = 2048;
  const int z = blockIdx.y;
  const int n0 = blockIdx.x * 64;
  __shared__ unsigned short tileG[64][66];
  __shared__ unsigned short tileW[64][66];
  const int t = threadIdx.x;
  const int rL = t >> 2, cq = (t & 3) * 16;
  const int nS = t >> 2, kc = (t & 3) * 16;
  float gwp = 0.f, bwp = 0.f;

  for (int kt = 0; kt < 16; ++kt) {
    {
      const float gs = g[(size_t)z * K + kt * 64 + rL];
      const float* src =
          W + (size_t)z * K * N + (size_t)(kt * 64 + rL) * N + n0 + cq;
#pragma unroll
      for (int i = 0; i < 16; i += 4) {
        f32x4 v = *(const f32x4*)(src + i);
#pragma unroll
        for (int j = 0; j < 4; ++j) {
          tileW[rL][cq + i + j] = (unsigned short)bf16r(v[j]);
          tileG[rL][cq + i + j] = (unsigned short)bf16r(gs * v[j]);
        }
      }
    }
    __syncthreads();
    {
      s16x8 o0, o1;
#pragma unroll
      for (int i = 0; i < 8; ++i) {
        o0[i] = tileG[kc + i][nS];
        o1[i] = tileG[kc + 8 + i][nS];
      }
#pragma unroll
      for (int i = 0; i < 16; ++i) {
        gwp += bf2f(tileG[kc + i][nS]);
        bwp += bvec[(size_t)z * K + kt * 64 + kc + i] * bf2f(tileW[kc + i][nS]);
      }
      unsigned short* dst =
          Wt + (size_t)z * N * K + (size_t)(n0 + nS) * K + kt * 64 + kc;
      *(s16x8*)dst = o0;
      *(s16x8*)(dst + 8) = o1;
    }
    __syncthreads();
  }
  gwp += __shfl_xor(gwp, 1);
  gwp += __shfl_xor(gwp, 2);
  bwp += __shfl_xor(bwp, 1);
  bwp += __shfl_xor(bwp, 2);
  if ((t & 3) == 0) {
    gw[(size_t)z * N + n0 + nS] = gwp;
    bw[(size_t)z * N + n0 + nS] = bwp + b2[(size_t)z * N + n0 + nS];
  }
}

// ---------------------------------------------------------------------------
// Deterministic row stats (sum, sumsq) of a z-major bf16 buffer.
// One block per row; fixed shuffle-tree order.
// ---------------------------------------------------------------------------
template <int W>
__global__ __launch_bounds__(256)
void stats_w_kernel(const unsigned short* __restrict__ buf,
                    float* __restrict__ stats) {
  constexpr int E = W / 256;
  const int z = blockIdx.x;
  const int b = blockIdx.y;
  const int tid = threadIdx.x;
  const unsigned short* row = buf + ((size_t)z * Bc + b) * W;
  float s = 0.f, s2 = 0.f;
  if constexpr (E == 4) {
    s16x4 t = *(const s16x4*)(row + tid * 4);
#pragma unroll
    for (int i = 0; i < 4; ++i) {
      float v = bf2f(t[i]);
      s += v;
      s2 += v * v;
    }
  } else {
    s16x8 t = *(const s16x8*)(row + tid * 8);
#pragma unroll
    for (int i = 0; i < 8; ++i) {
      float v = bf2f(t[i]);
      s += v;
      s2 += v * v;
    }
  }
#pragma unroll
  for (int o = 32; o > 0; o >>= 1) {
    s += __shfl_xor(s, o);
    s2 += __shfl_xor(s2, o);
  }
  __shared__ float red[2][4];
  const int w = tid >> 6;
  if ((tid & 63) == 0) {
    red[0][w] = s;
    red[1][w] = s2;
  }
  __syncthreads();
  if (tid == 0) {
    stats[((size_t)z * Bc + b) * 2 + 0] =
        red[0][0] + red[0][1] + red[0][2] + red[0][3];
    stats[((size_t)z * Bc + b) * 2 + 1] =
        red[1][0] + red[1][1] + red[1][2] + red[1][3];
  }
}

// ---------------------------------------------------------------------------
// 8-phase counted-vmcnt GEMM (r7/r9 schedule, paired-row 128B LDS, 0
// conflicts). z-major A: [z][2048][K]. GELU epilogue or FUSE (folded ln1).
// No epilogue atomics (r12 lesson: in-GEMM stats atomics cost ~250us).
// ---------------------------------------------------------------------------
template <int K, int N, int NBN, int GELU, int FUSE>
__global__ __launch_bounds__(512, 2)
void gemm8ph(const unsigned short* __restrict__ A,
             const unsigned short* __restrict__ Wt,
             const float* __restrict__ bias,
             unsigned short* __restrict__ outbuf,
             const float* __restrict__ gw, const float* __restrict__ bw,
             const float* __restrict__ stats1) {
  constexpr int NT = K / 64;
  constexpr int NIT = NT / 2;
  constexpr int NBM = 8;
  extern __shared__ __align__(16) char smem[];

  constexpr int nwg = 33 * NBM * NBN;
  constexpr int q = nwg >> 3, r = nwg & 7;
  const int orig = blockIdx.x;
  const int xcd = orig & 7;
  const int wgid =
      ((xcd < r) ? xcd * (q + 1) : r * (q + 1) + (xcd - r) * q) + (orig >> 3);
  const int z = wgid / (NBM * NBN);
  const int rem = wgid - z * (NBM * NBN);
  const int bm = rem / NBN, bn = rem - bm * NBN;

  const int tid = threadIdx.x, lane = tid & 63, wv = tid >> 6;
  const int wm = wv >> 2, wn = wv & 3;
  const int wr = wm * 128, wc = wn * 64;
  const int l15 = lane & 15, l4 = lane >> 4;

  f32x4 acc[8][4];
#pragma unroll
  for (int m = 0; m < 8; ++m)
#pragma unroll
    for (int n = 0; n < 4; ++n) {
      acc[m][n][0] = 0.f; acc[m][n][1] = 0.f;
      acc[m][n][2] = 0.f; acc[m][n][3] = 0.f;
    }

  const unsigned short* aRow[2];
  const unsigned short* bRow[2];
  {
    const unsigned short* Bbase = Wt + (size_t)z * N * K;
#pragma unroll
    for (int c = 0; c < 2; ++c) {
      const int rprime = wv * 16 + c * 8 + (lane >> 3);
      const int row = 2 * rprime + ((lane >> 2) & 1);
      const int chunk = (lane & 3) ^ (rprime & 3);
      aRow[c] = A + ((size_t)z * Bc + bm * 256 + row) * K + chunk * 8;
      bRow[c] = Bbase + (size_t)(bn * 256 + row) * K + chunk * 8;
    }
  }

  auto STAGE_A = [&](int t, int kh) {
    char* dst = smem + (t & 1) * 65536 + kh * 16384 + wv * 2048;
    const int ko = t * 64 + kh * 32;
#pragma unroll
    for (int c = 0; c < 2; ++c) gl_lds16(aRow[c] + ko, dst + c * 1024);
  };
  auto STAGE_B = [&](int t, int kh) {
    char* dst = smem + (t & 1) * 65536 + 32768 + kh * 16384 + wv * 2048;
    const int ko = t * 64 + kh * 32;
#pragma unroll
    for (int c = 0; c < 2; ++c) gl_lds16(bRow[c] + ko, dst + c * 1024);
  };
  s16x8 afr[4], bfr[4];
  auto LDA = [&](int d, int kh, int mh) {
#pragma unroll
    for (int m = 0; m < 4; ++m) {
      const int row = wr + (mh * 4 + m) * 16 + l15;
      const int rp = row >> 1;
      afr[m] = *(const s16x8*)(smem + d * 65536 + kh * 16384 + rp * 128 +
                               (row & 1) * 64 + ((l4 ^ (rp & 3)) << 4));
    }
  };
  auto LDB = [&](int d, int kh) {
#pragma unroll
    for (int n = 0; n < 4; ++n) {
      const int row = wc + n * 16 + l15;
      const int rp = row >> 1;
      bfr[n] = *(const s16x8*)(smem + d * 65536 + 32768 + kh * 16384 +
                               rp * 128 + (row & 1) * 64 +
                               ((l4 ^ (rp & 3)) << 4));
    }
  };

#define MFMA16(MH)                                                          \
  {                                                                         \
    __builtin_amdgcn_s_setprio(1);                                          \
    _Pragma("unroll") for (int m_ = 0; m_ < 4; ++m_) {                      \
      _Pragma("unroll") for (int n_ = 0; n_ < 4; ++n_) {                    \
        acc[(MH) * 4 + m_][n_] = __builtin_amdgcn_mfma_f32_16x16x32_bf16(   \
            afr[m_], bfr[n_], acc[(MH) * 4 + m_][n_], 0, 0, 0);             \
      }                                                                     \
    }                                                                       \
    __builtin_amdgcn_s_setprio(0);                                          \
  }

  STAGE_A(0, 0); STAGE_B(0, 0); STAGE_A(0, 1); STAGE_B(0, 1);
  STAGE_A(1, 0); STAGE_B(1, 0);
  VM4();
  BARw();

  for (int i = 0; i < NIT; ++i) {
    const int t0 = 2 * i, t1 = 2 * i + 1;
    LDA(0, 0, 0); LDB(0, 0);
    STAGE_A(t1, 1);
    BARw(); MFMA16(0); BARw();
    LDA(0, 0, 1);
    STAGE_B(t1, 1);
    BARw(); MFMA16(1); BARw();
    LDA(0, 1, 0); LDB(0, 1);
    if (t0 + 2 < NT) STAGE_A(t0 + 2, 0);
    BARw(); MFMA16(0); BARw();
    LDA(0, 1, 1);
    if (t0 + 2 < NT) STAGE_B(t0 + 2, 0);
    BARw(); MFMA16(1);
    VM4();
    BARw();
    LDA(1, 0, 0); LDB(1, 0);
    if (t0 + 2 < NT) STAGE_A(t0 + 2, 1);
    BARw(); MFMA16(0); BARw();
    LDA(1, 0, 1);
    if (t0 + 2 < NT) STAGE_B(t0 + 2, 1);
    BARw(); MFMA16(1); BARw();
    LDA(1, 1, 0); LDB(1, 1);
    if (t0 + 3 < NT) STAGE_A(t0 + 3, 0);
    BARw(); MFMA16(0); BARw();
    LDA(1, 1, 1);
    if (t0 + 3 < NT) STAGE_B(t0 + 3, 0);
    BARw(); MFMA16(1);
    VM4();
    BARw();
  }
#undef MFMA16

  float bsv[4], gwv[4], bwv[4];
#pragma unroll
  for (int n = 0; n < 4; ++n) {
    const int col = bn * 256 + wc + n * 16 + l15;
    if constexpr (FUSE) {
      gwv[n] = gw[(size_t)z * N + col];
      bwv[n] = bw[(size_t)z * N + col];
    } else {
      bsv[n] = bias[(size_t)z * N + col];
    }
  }

#pragma unroll
  for (int m = 0; m < 8; ++m) {
#pragma unroll
    for (int j = 0; j < 4; ++j) {
      const int grow = bm * 256 + wr + m * 16 + l4 * 4 + j;
      float mu = 0.f, rstd = 0.f;
      if constexpr (FUSE) {
        const float st0 = stats1[((size_t)z * Bc + grow) * 2 + 0];
        const float st1 = stats1[((size_t)z * Bc + grow) * 2 + 1];
        mu = st0 * (1.0f / K);
        const float var = st1 * (1.0f / K) - mu * mu;
        rstd = rsqrtf(var + 1e-5f);
      }
#pragma unroll
      for (int n = 0; n < 4; ++n) {
        const int col = bn * 256 + wc + n * 16 + l15;
        float v;
        if constexpr (FUSE) {
          v = rstd * acc[m][n][j] - (rstd * mu) * gwv[n] + bwv[n];
        } else {
          v = acc[m][n][j] + bsv[n];
        }
        if constexpr (GELU) v = 0.5f * v * (1.0f + erff(v * 0.70710678118f));
        outbuf[((size_t)z * Bc + grow) * N + col] = (unsigned short)bf16r(v);
      }
    }
  }
}

// ---------------------------------------------------------------------------
// Old-style fused GEMM (reg-staged). Split-precision query path (SPLITQ=1)
// and full fallback path. MODE1/MODE2 outputs are z-major.
// ---------------------------------------------------------------------------
template <int MODE, int SPLITQ>
__global__ __launch_bounds__(256, 2)
void gemm_fused(const float* __restrict__ x,
                const unsigned short* __restrict__ hbuf,
                const float* __restrict__ hqF,
                const float* __restrict__ Wmain, const float* __restrict__ Wq,
                const float* __restrict__ bmain, const float* __restrict__ bq,
                unsigned short* __restrict__ outH, float* __restrict__ outHq,
                unsigned short* __restrict__ outV, float* __restrict__ outQ) {
  constexpr int K = (MODE == 1) ? 2048 : 1024;
  constexpr int N = (MODE == 1) ? 1024 : 2048;
  constexpr int BK = 32;
  constexpr int NT = K / BK;

  const int z = blockIdx.z;
  const int bm = blockIdx.x;
  const int bn = blockIdx.y;
  const int tid = threadIdx.x;
  const int lane = tid & 63;
  const int wid = tid >> 6;
  const int wr = (wid >> 1) * 64;
  const int wc = (wid & 1) * 64;
  const int l15 = lane & 15;
  const int kb = lane >> 4;

  const float* Bp = SPLITQ ? Wq : (Wmain + (size_t)z * K * N);

  __shared__ short Als[1 + SPLITQ][128][32];
  __shared__ short Bls[1 + SPLITQ][128][32];

  const f32x4 vzero = {0.f, 0.f, 0.f, 0.f};
  f32x4 acc[4][4];
#pragma unroll
  for (int m = 0; m < 4; ++m)
#pragma unroll
    for (int n = 0; n < 4; ++n) acc[m][n] = vzero;

  const int ar = tid >> 1;
  const int ak = (tid & 1) * 16;
  const int grow = bm * 128 + ar;

  const float* ApF = nullptr;
  const unsigned short* ApH = nullptr;
  if constexpr (MODE == 1) {
    const int lsel = SPLITQ ? (Lc - 1) : z;
    ApF = x + (size_t)grow * (Lc * Dc) + (size_t)lsel * Dc + ak;
  } else if constexpr (SPLITQ == 1) {
    ApF = hqF + (size_t)grow * DBc + ak;
  } else {
    ApH = hbuf + ((size_t)z * Bc + grow) * DBc + ak;
  }

  const int bnL = tid & 127;
  const int bj = tid >> 7;
  const int c0 = ((bnL >> 1) & 3) ^ bj;
  const int kc0 = c0 * 8;
  const int kc1 = (c0 ^ 2) * 8;
  const float* Bcol = Bp + (size_t)bn * 128 + bnL;

  float aF[16];
  s16x8 aH0, aH1;
  float bF[16];

  auto loadA = [&](int kt) {
    if constexpr (MODE == 2 && SPLITQ == 0) {
      const unsigned short* p = ApH + kt * BK;
      aH0 = *(const s16x8*)p;
      aH1 = *(const s16x8*)(p + 8);
    } else {
      const float* p = ApF + kt * BK;
#pragma unroll
      for (int i = 0; i < 4; ++i) {
        f32x4 t = *(const f32x4*)(p + i * 4);
#pragma unroll
        for (int j = 0; j < 4; ++j) aF[i * 4 + j] = t[j];
      }
    }
  };
  auto loadB = [&](int kt) {
    const float* p0 = Bcol + (size_t)(kt * BK + kc0) * N;
    const float* p1 = Bcol + (size_t)(kt * BK + kc1) * N;
#pragma unroll
    for (int i = 0; i < 8; ++i) bF[i] = p0[(size_t)i * N];
#pragma unroll
    for (int i = 0; i < 8; ++i) bF[8 + i] = p1[(size_t)i * N];
  };
  auto writeLDS = [&]() {
    if constexpr (MODE == 2 && SPLITQ == 0) {
      *(s16x8*)&Als[0][ar][ak] = aH0;
      *(s16x8*)&Als[0][ar][ak + 8] = aH1;
    } else if constexpr (SPLITQ == 0) {
      *(s16x8*)&Als[0][ar][ak] = pack8(aF);
      *(s16x8*)&Als[0][ar][ak + 8] = pack8(aF + 8);
    } else {
      s16x8 h0, l0, h1, l1;
      split8(aF, h0, l0);
      split8(aF + 8, h1, l1);
      *(s16x8*)&Als[0][ar][ak] = h0;
      *(s16x8*)&Als[1][ar][ak] = l0;
      *(s16x8*)&Als[0][ar][ak + 8] = h1;
      *(s16x8*)&Als[1][ar][ak + 8] = l1;
    }
    if constexpr (SPLITQ == 0) {
      *(s16x8*)&Bls[0][bnL][kc0] = pack8(bF);
      *(s16x8*)&Bls[0][bnL][kc1] = pack8(bF + 8);
    } else {
      s16x8 h0, l0, h1, l1;
      split8(bF, h0, l0);
      split8(bF + 8, h1, l1);
      *(s16x8*)&Bls[0][bnL][kc0] = h0;
      *(s16x8*)&Bls[1][bnL][kc0] = l0;
      *(s16x8*)&Bls[0][bnL][kc1] = h1;
      *(s16x8*)&Bls[1][bnL][kc1] = l1;
    }
  };

  loadA(0);
  loadB(0);
  for (int kt = 0; kt < NT; ++kt) {
    __syncthreads();
    writeLDS();
    if (kt + 1 < NT) {
      loadA(kt + 1);
      loadB(kt + 1);
    }
    __syncthreads();
    s16x8 af[4], bfv[4];
#pragma unroll
    for (int m = 0; m < 4; ++m)
      af[m] = *(const s16x8*)&Als[0][wr + m * 16 + l15][kb * 8];
#pragma unroll
    for (int n = 0; n < 4; ++n)
      bfv[n] = *(const s16x8*)&Bls[0][wc + n * 16 + l15][kb * 8];
    if constexpr (SPLITQ == 1) {
      s16x8 afl[4], bfl[4];
#pragma unroll
      for (int m = 0; m < 4; ++m)
        afl[m] = *(const s16x8*)&Als[1][wr + m * 16 + l15][kb * 8];
#pragma unroll
      for (int n = 0; n < 4; ++n)
        bfl[n] = *(const s16x8*)&Bls[1][wc + n * 16 + l15][kb * 8];
#pragma unroll
      for (int m = 0; m < 4; ++m)
#pragma unroll
        for (int n = 0; n < 4; ++n) {
          acc[m][n] = __builtin_amdgcn_mfma_f32_16x16x32_bf16(
              af[m], bfv[n], acc[m][n], 0, 0, 0);
          acc[m][n] = __builtin_amdgcn_mfma_f32_16x16x32_bf16(
              af[m], bfl[n], acc[m][n], 0, 0, 0);
          acc[m][n] = __builtin_amdgcn_mfma_f32_16x16x32_bf16(
              afl[m], bfv[n], acc[m][n], 0, 0, 0);
        }
    } else {
#pragma unroll
      for (int m = 0; m < 4; ++m)
#pragma unroll
        for (int n = 0; n < 4; ++n)
          acc[m][n] = __builtin_amdgcn_mfma_f32_16x16x32_bf16(
              af[m], bfv[n], acc[m][n], 0, 0, 0);
    }
  }

  const float* biasP = SPLITQ ? bq : (bmain + (size_t)z * N);
#pragma unroll
  for (int m = 0; m < 4; ++m) {
    const int r0 = bm * 128 + wr + m * 16 + kb * 4;
#pragma unroll
    for (int n = 0; n < 4; ++n) {
      const int col = bn * 128 + wc + n * 16 + l15;
      const float bs = biasP[col];
#pragma unroll
      for (int j = 0; j < 4; ++j) {
        const int r = r0 + j;
        const float v = acc[m][n][j] + bs;
        if constexpr (MODE == 1 && SPLITQ == 0) {
          const float g = 0.5f * v * (1.0f + erff(v * 0.70710678118f));
          outH[((size_t)z * Bc + r) * DBc + col] = (unsigned short)bf16r(g);
        } else if constexpr (MODE == 1 && SPLITQ == 1) {
          const float g = 0.5f * v * (1.0f + erff(v * 0.70710678118f));
          outHq[(size_t)r * DBc + col] = g;
        } else if constexpr (MODE == 2 && SPLITQ == 0) {
          outV[((size_t)z * Bc + r) * Dc + col] = (unsigned short)bf16r(v);
        } else {
          const float zl =
              x[(size_t)r * (Lc * Dc) + (size_t)(Lc - 1) * Dc + col];
          const float t = zl + v;
          outQ[(size_t)r * Dc + col] = (t > 0.f) ? (1.f + t) : __expf(t);
        }
      }
    }
  }
}

// ---------------------------------------------------------------------------
// Row LayerNorm over last dim W, in place, z-major buffer (fallback only).
// ---------------------------------------------------------------------------
template <int W>
__global__ __launch_bounds__(256)
void ln_kernel(unsigned short* __restrict__ buf, const float* __restrict__ gmain,
               const float* __restrict__ bmain) {
  constexpr int E = W / 256;
  const int z = blockIdx.x;
  const int b = blockIdx.y;
  const int tid = threadIdx.x;
  unsigned short* row = buf + ((size_t)z * Bc + b) * W;
  float v[E];
  if constexpr (E == 4) {
    s16x4 t = *(const s16x4*)(row + tid * 4);
#pragma unroll
    for (int i = 0; i < 4; ++i) v[i] = bf2f(t[i]);
  } else {
    s16x8 t = *(const s16x8*)(row + tid * 8);
#pragma unroll
    for (int i = 0; i < 8; ++i) v[i] = bf2f(t[i]);
  }
  float s = 0.f, s2 = 0.f;
#pragma unroll
  for (int i = 0; i < E; ++i) {
    s += v[i];
    s2 += v[i] * v[i];
  }
#pragma unroll
  for (int o = 32; o > 0; o >>= 1) {
    s += __shfl_xor(s, o);
    s2 += __shfl_xor(s2, o);
  }
  __shared__ float red[2][4];
  const int w = tid >> 6;
  if ((tid & 63) == 0) {
    red[0][w] = s;
    red[1][w] = s2;
  }
  __syncthreads();
  s = red[0][0] + red[0][1] + red[0][2] + red[0][3];
  s2 = red[1][0] + red[1][1] + red[1][2] + red[1][3];
  const float mu = s * (1.0f / W);
  const float var = s2 * (1.0f / W) - mu * mu;
  const float rstd = rsqrtf(var + 1e-5f);
  const float* G = gmain + (size_t)z * W;
  const float* Bt = bmain + (size_t)z * W;
  if constexpr (E == 4) {
    f32x4 gv = *(const f32x4*)(G + tid * 4);
    f32x4 bv = *(const f32x4*)(Bt + tid * 4);
    s16x4 o;
#pragma unroll
    for (int i = 0; i < 4; ++i)
      o[i] = bf16r((v[i] - mu) * rstd * gv[i] + bv[i]);
    *(s16x4*)(row + tid * 4) = o;
  } else {
    f32x4 g0 = *(const f32x4*)(G + tid * 8);
    f32x4 g1 = *(const f32x4*)(G + tid * 8 + 4);
    f32x4 b0 = *(const f32x4*)(Bt + tid * 8);
    f32x4 b1 = *(const f32x4*)(Bt + tid * 8 + 4);
    s16x8 o;
#pragma unroll
    for (int i = 0; i < 4; ++i) {
      o[i] = bf16r((v[i] - mu) * rstd * g0[i] + b0[i]);
      o[i + 4] = bf16r((v[i + 4] - mu) * rstd * g1[i] + b1[i]);
    }
    *(s16x8*)(row + tid * 8) = o;
  }
}

// ---------------------------------------------------------------------------
// f32 LayerNorm for hq (2048 rows x 1024), in place.
// ---------------------------------------------------------------------------
__global__ __launch_bounds__(256)
void ln_f32_kernel(float* __restrict__ buf, const float* __restrict__ g,
                   const float* __restrict__ bb) {
  const int r = blockIdx.x;
  const int tid = threadIdx.x;
  float* row = buf + (size_t)r * DBc;
  f32x4 v = *(const f32x4*)(row + tid * 4);
  float s = 0.f, s2 = 0.f;
#pragma unroll
  for (int i = 0; i < 4; ++i) {
    s += v[i];
    s2 += v[i] * v[i];
  }
#pragma unroll
  for (int o = 32; o > 0; o >>= 1) {
    s += __shfl_xor(s, o);
    s2 += __shfl_xor(s2, o);
  }
  __shared__ float red[2][4];
  const int w = tid >> 6;
  if ((tid & 63) == 0) {
    red[0][w] = s;
    red[1][w] = s2;
  }
  __syncthreads();
  s = red[0][0] + red[0][1] + red[0][2] + red[0][3];
  s2 = red[1][0] + red[1][1] + red[1][2] + red[1][3];
  const float mu = s * (1.0f / DBc);
  const float var = s2 * (1.0f / DBc) - mu * mu;
  const float rstd = rsqrtf(var + 1e-5f);
  f32x4 gv = *(const f32x4*)(g + tid * 4);
  f32x4 bv = *(const f32x4*)(bb + tid * 4);
  f32x4 o;
#pragma unroll
  for (int i = 0; i < 4; ++i) o[i] = (v[i] - mu) * rstd * gv[i] + bv[i];
  *(f32x4*)(row + tid * 4) = o;
}

// ---------------------------------------------------------------------------
// Final attention with fused ln2, z-major vals/stats (r9-proven form).
// ---------------------------------------------------------------------------
__global__ __launch_bounds__(256)
void attn_kernel(const float* __restrict__ x, const float* __restrict__ query,
                 const float* __restrict__ keys,
                 const unsigned short* __restrict__ vals,
                 const float* __restrict__ stats, const float* __restrict__ g2,
                 const float* __restrict__ b2ln, float* __restrict__ out) {
  const int b = blockIdx.x;
  const int tid = threadIdx.x;
  const int d0 = tid * 8;

  float qv[8];
  {
    f32x4 t0 = *(const f32x4*)(query + (size_t)b * Dc + d0);
    f32x4 t1 = *(const f32x4*)(query + (size_t)b * Dc + d0 + 4);
#pragma unroll
    for (int i = 0; i < 4; ++i) {
      qv[i] = t0[i];
      qv[i + 4] = t1[i];
    }
  }
  float s[33];
#pragma unroll
  for (int l = 0; l < 33; ++l) {
    const float* kp = keys + (size_t)l * Dc + d0;
    f32x4 k0 = *(const f32x4*)kp;
    f32x4 k1 = *(const f32x4*)(kp + 4);
    float t = 0.f;
#pragma unroll
    for (int i = 0; i < 4; ++i) t += qv[i] * k0[i] + qv[i + 4] * k1[i];
    s[l] = t;
  }
#pragma unroll
  for (int l = 0; l < 33; ++l) {
    float v = s[l];
#pragma unroll
    for (int o = 32; o > 0; o >>= 1) v += __shfl_xor(v, o);
    s[l] = v;
  }
  __shared__ float sred[4][33];
  __shared__ float sl[33];
  const int w = tid >> 6;
  if ((tid & 63) == 0) {
#pragma unroll
    for (int l = 0; l < 33; ++l) sred[w][l] = s[l];
  }
  __syncthreads();
  if (tid < 33)
    sl[tid] = sred[0][tid] + sred[1][tid] + sred[2][tid] + sred[3][tid];
  __syncthreads();

  float m = -1e30f;
#pragma unroll
  for (int l = 0; l < 33; ++l) m = fmaxf(m, sl[l]);
  float p[33];
  float sum = 0.f;
#pragma unroll
  for (int l = 0; l < 33; ++l) {
    p[l] = __expf(sl[l] - m);
    sum += p[l];
  }
  const float inv = 1.0f / sum;

  float acc8[8];
  {
    const float* zl = x + (size_t)b * (Lc * Dc) + (size_t)(Lc - 1) * Dc + d0;
    f32x4 z0 = *(const f32x4*)zl;
    f32x4 z1 = *(const f32x4*)(zl + 4);
#pragma unroll
    for (int i = 0; i < 4; ++i) {
      acc8[i] = z0[i];
      acc8[i + 4] = z1[i];
    }
  }
#pragma unroll
  for (int l = 0; l < 33; ++l) {
    const float st0 = stats[((size_t)l * Bc + b) * 2 + 0];
    const float st1 = stats[((size_t)l * Bc + b) * 2 + 1];
    const float mu = st0 * (1.0f / Dc);
    const float var = st1 * (1.0f / Dc) - mu * mu;
    const float rstd = rsqrtf(var + 1e-5f);
    const float a = p[l] * inv;
    s16x8 vv = *(const s16x8*)(vals + ((size_t)l * Bc + b) * Dc + d0);
    const float* gp = g2 + (size_t)l * Dc + d0;
    const float* bp = b2ln + (size_t)l * Dc + d0;
    f32x4 g0 = *(const f32x4*)gp, g1 = *(const f32x4*)(gp + 4);
    f32x4 b0 = *(const f32x4*)bp, b1 = *(const f32x4*)(bp + 4);
#pragma unroll
    for (int i = 0; i < 4; ++i) {
      acc8[i] += a * ((bf2f(vv[i]) - mu) * rstd * g0[i] + b0[i]);
      acc8[i + 4] += a * ((bf2f(vv[i + 4]) - mu) * rstd * g1[i] + b1[i]);
    }
  }
  f32x4 o0, o1;
#pragma unroll
  for (int i = 0; i < 4; ++i) {
    o0[i] = acc8[i];
    o1[i] = acc8[i + 4];
  }
  *(f32x4*)(out + (size_t)b * Dc + d0) = o0;
  *(f32x4*)(out + (size_t)b * Dc + d0 + 4) = o1;
}

// ---------------------------------------------------------------------------
extern "C" void kernel_launch(void* const* d_in, const int* in_sizes, int n_in,
                              void* d_out, int out_size, void* d_ws,
                              size_t ws_size, hipStream_t stream) {
  const float* x = (const float*)d_in[0];
  const float* pe = (const float*)d_in[1];
  const float* Wk = (const float*)d_in[2];
  const float* W1 = (const float*)d_in[3];
  const float* b1 = (const float*)d_in[4];
  const float* ln1g = (const float*)d_in[5];
  const float* ln1b = (const float*)d_in[6];
  const float* W2 = (const float*)d_in[7];
  const float* b2 = (const float*)d_in[8];
  const float* ln2g = (const float*)d_in[9];
  const float* ln2b = (const float*)d_in[10];
  const float* Wq1 = (const float*)d_in[11];
  const float* bq1 = (const float*)d_in[12];
  const float* lnqg = (const float*)d_in[13];
  const float* lnqb = (const float*)d_in[14];
  const float* Wq2 = (const float*)d_in[15];
  const float* bq2 = (const float*)d_in[16];
  float* out = (float*)d_out;
  char* ws = (char*)d_ws;

  // ws layout (bytes), lifetime-aliased (r9 layout):
  //   keys   @ 0            (270,336)
  //   query  @ 270,336      (16,777,216)
  //   hq     @ 17,047,552   (8,388,608)
  //   stats1 @ 25,436,160   (540,672)   h row stats (deterministic -> FUSE)
  //   stats2 @ 25,976,832   (540,672)   vals row stats (deterministic -> attn)
  //   gw     @ 26,517,504   (270,336)
  //   bw     @ 26,787,840   (270,336)
  //   h      @ 27,058,176   (138,412,032)  bf16 [33][2048][1024] z-major
  //   xbf    @ 165,470,208  (276,824,064)  cvt->G1
  //   vals   @ 165,470,208  (ALIAS xbf: G2->attn)
  //   W1t    @ 442,294,272  (138,412,032)  t1->G1
  //   W2gt   @ 442,294,272  (ALIAS: t2g->G2)  -> end 580,706,304
  float* keysP = (float*)(ws);
  float* queryP = (float*)(ws + 270336);
  float* hqP = (float*)(ws + 17047552);
  float* stats1P = (float*)(ws + 25436160);
  float* stats2P = (float*)(ws + 25976832);
  float* gwP = (float*)(ws + 26517504);
  float* bwP = (float*)(ws + 26787840);
  unsigned short* hP = (unsigned short*)(ws + 27058176);
  unsigned short* xbfP = (unsigned short*)(ws + 165470208);
  unsigned short* valsP = (unsigned short*)(ws + 165470208);
  unsigned short* W1tP = (unsigned short*)(ws + 442294272);
  unsigned short* W2gtP = (unsigned short*)(ws + 442294272);

  const bool fast = (ws_size >= 580706304ull);
  bool use8 = fast;
  if (fast) {
    if (hipFuncSetAttribute(
            reinterpret_cast<const void*>(&gemm8ph<2048, 1024, 4, 1, 0>),
            hipFuncAttributeMaxDynamicSharedMemorySize, 131072) != hipSuccess)
      use8 = false;
    if (hipFuncSetAttribute(
            reinterpret_cast<const void*>(&gemm8ph<1024, 2048, 8, 0, 1>),
            hipFuncAttributeMaxDynamicSharedMemorySize, 131072) != hipSuccess)
      use8 = false;
  }

  keys_kernel<<<dim3(33, 8), 256, 0, stream>>>(pe, Wk, keysP);

  gemm_fused<1, 1><<<dim3(16, 8, 1), 256, 0, stream>>>(
      x, nullptr, nullptr, nullptr, Wq1, nullptr, bq1, nullptr, hqP, nullptr,
      nullptr);

  if (use8) {
    cvt_perm_kernel<<<dim3(2048, 33), 256, 0, stream>>>(x, xbfP);
    transpose_w<2048, 1024><<<dim3(32, 16, 33), 256, 0, stream>>>(W1, W1tP);
    gemm8ph<2048, 1024, 4, 1, 0>
        <<<dim3(33 * 8 * 4), 512, 131072, stream>>>(xbfP, W1tP, b1, hP,
                                                    nullptr, nullptr, nullptr);
    stats_w_kernel<1024><<<dim3(33, 2048), 256, 0, stream>>>(hP, stats1P);
    ln_f32_kernel<<<dim3(2048), 256, 0, stream>>>(hqP, lnqg, lnqb);
    transpose_w2g<<<dim3(32, 33), 256, 0, stream>>>(W2, ln1g, ln1b, b2, W2gtP,
                                                    gwP, bwP);
    gemm8ph<1024, 2048, 8, 0, 1>
        <<<dim3(33 * 8 * 8), 512, 131072, stream>>>(hP, W2gtP, nullptr, valsP,
                                                    gwP, bwP, stats1P);
    stats_w_kernel<2048><<<dim3(33, 2048), 256, 0, stream>>>(valsP, stats2P);
  } else {
    gemm_fused<1, 0><<<dim3(16, 8, 33), 256, 0, stream>>>(
        x, nullptr, nullptr, W1, nullptr, b1, nullptr, hP, nullptr, nullptr,
        nullptr);
    ln_kernel<1024><<<dim3(33, 2048), 256, 0, stream>>>(hP, ln1g, ln1b);
    ln_f32_kernel<<<dim3(2048), 256, 0, stream>>>(hqP, lnqg, lnqb);
    gemm_fused<2, 0><<<dim3(16, 16, 33), 256, 0, stream>>>(
        x, hP, nullptr, W2, nullptr, b2, nullptr, nullptr, nullptr, valsP,
        nullptr);
    stats_w_kernel<2048><<<dim3(33, 2048), 256, 0, stream>>>(valsP, stats2P);
  }

  gemm_fused<2, 1><<<dim3(16, 16, 1), 256, 0, stream>>>(
      x, nullptr, hqP, nullptr, Wq2, nullptr, bq2, nullptr, nullptr, nullptr,
      queryP);

  attn_kernel<<<dim3(2048), 256, 0, stream>>>(x, queryP, keysP, valsP,
                                              stats2P, ln2g, ln2b, out);
}